// Round 5
// baseline (2682.432 us; speedup 1.0000x reference)
//
#include <hip/hip_runtime.h>
#include <stdint.h>
#include <stddef.h>

// QuantizedColumnParallel: y[4096,16384] = x[4096,4096] @ (wq[16384,4096]*scale)^T + bias
// R5: int8 path, DOUBLE-buffered LDS (64 KB) => 2 blocks/CU co-resident.
// Rationale: R4 counters showed LDS segment (576 cyc) and MFMA segment (653 cyc)
// serialized by the 8-wave lockstep at 1 block/CU. Two barrier-independent
// blocks/CU co-schedule the pipes (m114). Stage t+1 fully in P1 of tile t;
// vmcnt(0) deferred to after P2 MFMA (~1300 cyc slack > 900 cyc HBM).

#define M_TOT 4096
#define N_TOT 16384
#define K_TOT 4096
#define NT    64          // K-tiles

typedef __attribute__((ext_vector_type(4))) int      v4i;
typedef __attribute__((ext_vector_type(8))) _Float16 f16x8;
typedef __attribute__((ext_vector_type(4))) float    f32x4;

#define GLOAD_LDS16(g, l) __builtin_amdgcn_global_load_lds(                  \
    (const __attribute__((address_space(1))) void*)(g),                      \
    (__attribute__((address_space(3))) void*)(l), 16, 0, 0)

// ---------------- conversion pre-passes ----------------

// x: one block per row (4096 f32). Row max -> sx, quantize to int8.
__global__ __launch_bounds__(256) void cvt_x_i8(const float* __restrict__ x,
                                                signed char* __restrict__ o,
                                                float* __restrict__ sx) {
  const int row = blockIdx.x;
  const int tid = threadIdx.x;
  const float* xr = x + (size_t)row * K_TOT;
  float4 v[4];
  float mx = 0.f;
#pragma unroll
  for (int j = 0; j < 4; ++j) {
    v[j] = ((const float4*)xr)[tid * 4 + j];
    mx = fmaxf(mx, fmaxf(fmaxf(fabsf(v[j].x), fabsf(v[j].y)),
                         fmaxf(fabsf(v[j].z), fabsf(v[j].w))));
  }
#pragma unroll
  for (int off = 32; off; off >>= 1) mx = fmaxf(mx, __shfl_xor(mx, off));
  __shared__ float wm[4];
  if ((tid & 63) == 0) wm[tid >> 6] = mx;
  __syncthreads();
  const float m4 = fmaxf(fmaxf(wm[0], wm[1]), fmaxf(wm[2], wm[3]));
  const float smax = fmaxf(m4, 1e-6f);
  const float inv  = 127.0f / smax;
  if (tid == 0) sx[row] = smax / 127.0f;
  int p[4];
#pragma unroll
  for (int j = 0; j < 4; ++j) {
    int q0 = (int)rintf(v[j].x * inv), q1 = (int)rintf(v[j].y * inv);
    int q2 = (int)rintf(v[j].z * inv), q3 = (int)rintf(v[j].w * inv);
    q0 = max(-127, min(127, q0)); q1 = max(-127, min(127, q1));
    q2 = max(-127, min(127, q2)); q3 = max(-127, min(127, q3));
    p[j] = (q0 & 255) | ((q1 & 255) << 8) | ((q2 & 255) << 16) | (q3 << 24);
  }
  ((int4*)(o + (size_t)row * K_TOT))[tid] = make_int4(p[0], p[1], p[2], p[3]);
}

// w: int32 (-127..127) -> int8, 16 elems/thread.
__global__ __launch_bounds__(256) void cvt_w_i8(const int* __restrict__ w,
                                                signed char* __restrict__ o, int n16) {
  const int stride = gridDim.x * blockDim.x;
  for (int i = blockIdx.x * blockDim.x + threadIdx.x; i < n16; i += stride) {
    int p[4];
#pragma unroll
    for (int j = 0; j < 4; ++j) {
      int4 a = ((const int4*)w)[i * 4 + j];
      p[j] = (a.x & 255) | ((a.y & 255) << 8) | ((a.z & 255) << 16) | (a.w << 24);
    }
    ((int4*)o)[i] = make_int4(p[0], p[1], p[2], p[3]);
  }
}

// ---------------- i8 GEMM: 256^2 tile, 2 phases/K-tile, double-buffered ----------------

// Stage one 256x64-byte region (16 KiB): 2 x global_load_lds(16B)/thread.
// LDS dest linear; XOR swizzle on GLOBAL source chunk (rule #21). Conflict-free
// verified in R3/R4 (SQ_LDS_BANK_CONFLICT = 0).
__device__ __forceinline__ void stage_i8(const signed char* __restrict__ g,
                                         size_t kbyte, signed char* l, int tid) {
#pragma unroll
  for (int j = 0; j < 2; ++j) {
    const int ci  = j * 512 + tid;       // 0..1023 16B-chunks
    const int row = ci >> 2;             // 0..255
    const int sc  = (ci & 3) ^ ((row >> 1) & 3);
    GLOAD_LDS16(g + (size_t)row * K_TOT + kbyte + sc * 16, l + ci * 16);
  }
}

// Swizzled fragment read: row r, 16B chunk hi (0..3). 2-way aliasing = free.
__device__ __forceinline__ v4i fragi(const signed char* region, int r, int hi) {
  return *(const v4i*)(region + r * 64 + ((hi ^ ((r >> 1) & 3)) << 4));
}

#define BAR()    __builtin_amdgcn_s_barrier()
#define LGKM0()  do { asm volatile("s_waitcnt lgkmcnt(0)" ::: "memory"); \
                      __builtin_amdgcn_sched_barrier(0); } while (0)

__global__ __launch_bounds__(512, 4) void gemm_i8(
    const signed char* __restrict__ A8, const signed char* __restrict__ B8,
    const float* __restrict__ sx, const float* __restrict__ scale_p,
    const float* __restrict__ bias, float* __restrict__ out)
{
  // lds[buf(2)][A=0|B=1][256*64 bytes] = 64 KiB  -> 2 blocks/CU
  __shared__ __align__(16) signed char lds[2][2][16384];

  const int tid  = threadIdx.x;
  const int lane = tid & 63;
  const int wave = tid >> 6;
  const int wr = wave >> 2;            // 0..1 (M)
  const int wc = wave & 3;             // 0..3 (N)
  const int lr = lane & 15;
  const int hi = lane >> 4;

  // XCD-aware swizzle: 1024 wg, 8 XCDs, 128 contiguous per XCD; bm fast.
  const int bid = blockIdx.x;
  const int wg  = (bid & 7) * 128 + (bid >> 3);
  const int bm  = wg & 15;
  const int bn  = wg >> 4;
  const int arow0 = bm * 256;
  const int brow0 = bn * 256;

  const signed char* Ag = A8 + (size_t)arow0 * K_TOT;
  const signed char* Bg = B8 + (size_t)brow0 * K_TOT;

  v4i acc[8][4];
#pragma unroll
  for (int m = 0; m < 8; ++m)
#pragma unroll
    for (int n = 0; n < 4; ++n)
      acc[m][n] = (v4i){0, 0, 0, 0};

  // ---- prologue: tile0 -> buf0, drain, go. (tile1 staged during tile0 P1)
  stage_i8(Ag, 0, &lds[0][0][0], tid);
  stage_i8(Bg, 0, &lds[0][1][0], tid);
  asm volatile("s_waitcnt vmcnt(0)" ::: "memory");
  __builtin_amdgcn_sched_barrier(0);
  BAR();

  v4i af[4], bf[4];

  for (int t = 0; t < NT; ++t) {
    const int b = t & 1;
    const signed char* At = &lds[b][0][0];
    const signed char* Bt = &lds[b][1][0];
    const size_t k1 = (size_t)(t + 1) * 64;

    // ---- P1: read af0-3 + bf0-3; stage FULL tile t+1 into buf^1; MFMA acc[0..3]
#pragma unroll
    for (int m = 0; m < 4; ++m) af[m] = fragi(At, wr * 128 + m * 16 + lr, hi);
#pragma unroll
    for (int n = 0; n < 4; ++n) bf[n] = fragi(Bt, wc * 64 + n * 16 + lr, hi);
    if (t + 1 < NT) {
      stage_i8(Ag, k1, &lds[b ^ 1][0][0], tid);
      stage_i8(Bg, k1, &lds[b ^ 1][1][0], tid);
    }
    BAR();
    LGKM0();
    __builtin_amdgcn_s_setprio(1);
#pragma unroll
    for (int m = 0; m < 4; ++m)
#pragma unroll
      for (int n = 0; n < 4; ++n)
        acc[m][n] = __builtin_amdgcn_mfma_i32_16x16x64_i8(af[m], bf[n], acc[m][n], 0, 0, 0);
    __builtin_amdgcn_s_setprio(0);
    BAR();

    // ---- P2: read af4-7 (bf held); MFMA acc[4..7]; THEN drain staging loads
    // (issue->wait distance ~= P1-MFMA + P2 full ~= 1300 cyc > HBM ~900).
#pragma unroll
    for (int m = 0; m < 4; ++m) af[m] = fragi(At, wr * 128 + 64 + m * 16 + lr, hi);
    BAR();
    LGKM0();
    __builtin_amdgcn_s_setprio(1);
#pragma unroll
    for (int m = 0; m < 4; ++m)
#pragma unroll
      for (int n = 0; n < 4; ++n)
        acc[4 + m][n] = __builtin_amdgcn_mfma_i32_16x16x64_i8(af[m], bf[n], acc[4 + m][n], 0, 0, 0);
    __builtin_amdgcn_s_setprio(0);
    asm volatile("s_waitcnt vmcnt(0)" ::: "memory");   // tile t+1 landed
    __builtin_amdgcn_sched_barrier(0);
    BAR();
  }

  // ---- epilogue: y = acc * (sx[row]*scale) + bias.
  // C/D map (dtype-independent): col=lane&15, row=(lane>>4)*4+reg.
  const float s = scale_p[0];
  float bv[4];
#pragma unroll
  for (int n = 0; n < 4; ++n) bv[n] = bias[brow0 + wc * 64 + n * 16 + lr];
#pragma unroll
  for (int mi = 0; mi < 8; ++mi) {
    const int row0 = arow0 + wr * 128 + (mi >> 2) * 64 + (mi & 3) * 16 + hi * 4;
    float sc4[4];
#pragma unroll
    for (int j = 0; j < 4; ++j) sc4[j] = sx[row0 + j] * s;
#pragma unroll
    for (int n = 0; n < 4; ++n) {
      const int col = brow0 + wc * 64 + n * 16 + lr;
      const v4i v = acc[mi][n];
#pragma unroll
      for (int j = 0; j < 4; ++j)
        out[(size_t)(row0 + j) * N_TOT + col] = (float)v[j] * sc4[j] + bv[n];
    }
  }
}

// ---------------- fallback (no workspace): f16 DIRECT 128^2 kernel ----------------

__global__ __launch_bounds__(256) void gemm_direct(
    const float* __restrict__ Xf, const int* __restrict__ Wq,
    const float* __restrict__ scale_p, const float* __restrict__ bias,
    float* __restrict__ out)
{
  __shared__ _Float16 ldsA[128 * 64];
  __shared__ _Float16 ldsB[128 * 64];
  const int tid = threadIdx.x, lane = tid & 63, wave = tid >> 6;
  const int wr = wave >> 1, wc = wave & 1;
  const int bid = blockIdx.x;
  const int wg  = (bid & 7) * 512 + (bid >> 3);
  const int arow0 = (wg & 31) * 128, brow0 = (wg >> 5) * 128;
  f32x4 acc[4][4];
#pragma unroll
  for (int m = 0; m < 4; ++m)
#pragma unroll
    for (int n = 0; n < 4; ++n) acc[m][n] = (f32x4){0.f, 0.f, 0.f, 0.f};
  const int srow = tid >> 3, schunk = tid & 7;
  const int lr = lane & 15, hi = lane >> 4;
  for (int kt = 0; kt < K_TOT / 64; ++kt) {
    const size_t kbase = (size_t)kt * 64;
    __syncthreads();
#pragma unroll
    for (int i = 0; i < 4; ++i) {
      const int row = i * 32 + srow;
      const int p = schunk ^ (row & 7);
      const float* gx = Xf + (size_t)(arow0 + row) * K_TOT + kbase + schunk * 8;
      const int*   gw = Wq + (size_t)(brow0 + row) * K_TOT + kbase + schunk * 8;
      float4 x0 = ((const float4*)gx)[0];
      float4 x1 = ((const float4*)gx)[1];
      int4   w0 = ((const int4*)gw)[0];
      int4   w1 = ((const int4*)gw)[1];
      f16x8 ha = { (_Float16)x0.x, (_Float16)x0.y, (_Float16)x0.z, (_Float16)x0.w,
                   (_Float16)x1.x, (_Float16)x1.y, (_Float16)x1.z, (_Float16)x1.w };
      f16x8 hb = { (_Float16)w0.x, (_Float16)w0.y, (_Float16)w0.z, (_Float16)w0.w,
                   (_Float16)w1.x, (_Float16)w1.y, (_Float16)w1.z, (_Float16)w1.w };
      *(f16x8*)(ldsA + row * 64 + p * 8) = ha;
      *(f16x8*)(ldsB + row * 64 + p * 8) = hb;
    }
    __syncthreads();
#pragma unroll
    for (int s2 = 0; s2 < 2; ++s2) {
      f16x8 af2[4], bf2[4];
#pragma unroll
      for (int m = 0; m < 4; ++m) {
        const int r = wr * 64 + m * 16 + lr;
        af2[m] = *(const f16x8*)(ldsA + r * 64 + (((s2 * 4 + hi) ^ (r & 7)) * 8));
      }
#pragma unroll
      for (int n = 0; n < 4; ++n) {
        const int r = wc * 64 + n * 16 + lr;
        bf2[n] = *(const f16x8*)(ldsB + r * 64 + (((s2 * 4 + hi) ^ (r & 7)) * 8));
      }
#pragma unroll
      for (int m = 0; m < 4; ++m)
#pragma unroll
        for (int n = 0; n < 4; ++n)
          acc[m][n] = __builtin_amdgcn_mfma_f32_16x16x32_f16(af2[m], bf2[n], acc[m][n], 0, 0, 0);
    }
  }
  const float s = scale_p[0];
#pragma unroll
  for (int n = 0; n < 4; ++n) {
    const int col = brow0 + wc * 64 + n * 16 + lr;
    const float bvv = bias[col];
#pragma unroll
    for (int m = 0; m < 4; ++m) {
      const int row0 = arow0 + wr * 64 + m * 16 + hi * 4;
      const f32x4 v = acc[m][n];
#pragma unroll
      for (int j = 0; j < 4; ++j)
        out[(size_t)(row0 + j) * N_TOT + col] = v[j] * s + bvv;
    }
  }
}

// ---------------- launch ----------------

extern "C" void kernel_launch(void* const* d_in, const int* in_sizes, int n_in,
                              void* d_out, int out_size, void* d_ws, size_t ws_size,
                              hipStream_t stream) {
  const float* x     = (const float*)d_in[0];
  const int*   wq    = (const int*)d_in[1];
  const float* scale = (const float*)d_in[2];
  const float* bias  = (const float*)d_in[3];
  float*       out   = (float*)d_out;

  const size_t nA = (size_t)M_TOT * K_TOT;   // 16.7M
  const size_t nB = (size_t)N_TOT * K_TOT;   // 67.1M
  const size_t need = nA + nB + M_TOT * sizeof(float);  // ~84 MiB

  if (ws_size >= need) {
    signed char* A8 = (signed char*)d_ws;
    signed char* B8 = A8 + nA;
    float*       sx = (float*)(B8 + nB);
    cvt_x_i8<<<M_TOT, 256, 0, stream>>>(x, A8, sx);
    cvt_w_i8<<<2048, 256, 0, stream>>>(wq, B8, (int)(nB / 16));
    gemm_i8<<<(M_TOT / 256) * (N_TOT / 256), 512, 0, stream>>>(A8, B8, sx, scale, bias, out);
  } else {
    gemm_direct<<<(M_TOT / 128) * (N_TOT / 128), 256, 0, stream>>>(x, wq, scale, bias, out);
  }
}

// Round 6
// 432.353 us; speedup vs baseline: 6.2043x; 6.2043x over previous
//
#include <hip/hip_runtime.h>
#include <stdint.h>
#include <stddef.h>

// QuantizedColumnParallel: y[4096,16384] = x[4096,4096] @ (wq[16384,4096]*scale)^T + bias
// R6: int8, 256^2 tile, triple-buffered (96 KB, 1 block/CU), ONE barrier per K-tile,
// no asm lgkm pins -> compiler emits fine-grained lgkmcnt and interleaves ds_read
// with MFMA drain (m97 behavior). Counted vmcnt(4) keeps tile t+2 in flight.
// R5 lesson: launch_bounds(512,4) starved registers (acc alone = 128/lane) -> spill
// -> 10.8 GB scratch traffic. Stay at (512,2).

#define M_TOT 4096
#define N_TOT 16384
#define K_TOT 4096
#define NT    64          // K-tiles

typedef __attribute__((ext_vector_type(4))) int      v4i;
typedef __attribute__((ext_vector_type(8))) _Float16 f16x8;
typedef __attribute__((ext_vector_type(4))) float    f32x4;

#define GLOAD_LDS16(g, l) __builtin_amdgcn_global_load_lds(                  \
    (const __attribute__((address_space(1))) void*)(g),                      \
    (__attribute__((address_space(3))) void*)(l), 16, 0, 0)

// ---------------- conversion pre-passes ----------------

// x: one block per row (4096 f32). Row max -> sx, quantize to int8.
__global__ __launch_bounds__(256) void cvt_x_i8(const float* __restrict__ x,
                                                signed char* __restrict__ o,
                                                float* __restrict__ sx) {
  const int row = blockIdx.x;
  const int tid = threadIdx.x;
  const float* xr = x + (size_t)row * K_TOT;
  float4 v[4];
  float mx = 0.f;
#pragma unroll
  for (int j = 0; j < 4; ++j) {
    v[j] = ((const float4*)xr)[tid * 4 + j];
    mx = fmaxf(mx, fmaxf(fmaxf(fabsf(v[j].x), fabsf(v[j].y)),
                         fmaxf(fabsf(v[j].z), fabsf(v[j].w))));
  }
#pragma unroll
  for (int off = 32; off; off >>= 1) mx = fmaxf(mx, __shfl_xor(mx, off));
  __shared__ float wm[4];
  if ((tid & 63) == 0) wm[tid >> 6] = mx;
  __syncthreads();
  const float m4 = fmaxf(fmaxf(wm[0], wm[1]), fmaxf(wm[2], wm[3]));
  const float smax = fmaxf(m4, 1e-6f);
  const float inv  = 127.0f / smax;
  if (tid == 0) sx[row] = smax / 127.0f;
  int p[4];
#pragma unroll
  for (int j = 0; j < 4; ++j) {
    int q0 = (int)rintf(v[j].x * inv), q1 = (int)rintf(v[j].y * inv);
    int q2 = (int)rintf(v[j].z * inv), q3 = (int)rintf(v[j].w * inv);
    q0 = max(-127, min(127, q0)); q1 = max(-127, min(127, q1));
    q2 = max(-127, min(127, q2)); q3 = max(-127, min(127, q3));
    p[j] = (q0 & 255) | ((q1 & 255) << 8) | ((q2 & 255) << 16) | (q3 << 24);
  }
  ((int4*)(o + (size_t)row * K_TOT))[tid] = make_int4(p[0], p[1], p[2], p[3]);
}

// w: int32 (-127..127) -> int8, 16 elems/thread.
__global__ __launch_bounds__(256) void cvt_w_i8(const int* __restrict__ w,
                                                signed char* __restrict__ o, int n16) {
  const int stride = gridDim.x * blockDim.x;
  for (int i = blockIdx.x * blockDim.x + threadIdx.x; i < n16; i += stride) {
    int p[4];
#pragma unroll
    for (int j = 0; j < 4; ++j) {
      int4 a = ((const int4*)w)[i * 4 + j];
      p[j] = (a.x & 255) | ((a.y & 255) << 8) | ((a.z & 255) << 16) | (a.w << 24);
    }
    ((int4*)o)[i] = make_int4(p[0], p[1], p[2], p[3]);
  }
}

// ---------------- i8 GEMM: 256^2 tile, 1 barrier per K-tile, triple-buffered ----------------

// Stage one 256x64-byte region (16 KiB): 2 x global_load_lds(16B)/thread.
// LDS dest linear; XOR swizzle on GLOBAL source chunk (rule #21). Conflict-free
// verified R3/R4 (SQ_LDS_BANK_CONFLICT = 0).
__device__ __forceinline__ void stage_i8(const signed char* __restrict__ g,
                                         size_t kbyte, signed char* l, int tid) {
#pragma unroll
  for (int j = 0; j < 2; ++j) {
    const int ci  = j * 512 + tid;       // 0..1023 16B-chunks
    const int row = ci >> 2;             // 0..255
    const int sc  = (ci & 3) ^ ((row >> 1) & 3);
    GLOAD_LDS16(g + (size_t)row * K_TOT + kbyte + sc * 16, l + ci * 16);
  }
}

// Swizzled fragment read: row r, 16B chunk hi (0..3). 2-way aliasing = free.
__device__ __forceinline__ v4i fragi(const signed char* region, int r, int hi) {
  return *(const v4i*)(region + r * 64 + ((hi ^ ((r >> 1) & 3)) << 4));
}

#define BAR()    __builtin_amdgcn_s_barrier()

__global__ __launch_bounds__(512, 2) void gemm_i8(
    const signed char* __restrict__ A8, const signed char* __restrict__ B8,
    const float* __restrict__ sx, const float* __restrict__ scale_p,
    const float* __restrict__ bias, float* __restrict__ out)
{
  // lds[buf(3)][A=0|B=1][256*64 bytes] = 96 KiB -> 1 block/CU
  __shared__ __align__(16) signed char lds[3][2][16384];

  const int tid  = threadIdx.x;
  const int lane = tid & 63;
  const int wave = tid >> 6;
  const int wr = wave >> 2;            // 0..1 (M)
  const int wc = wave & 3;             // 0..3 (N)
  const int lr = lane & 15;
  const int hi = lane >> 4;

  // XCD-aware swizzle: 1024 wg, 8 XCDs, 128 contiguous per XCD; bm fast.
  const int bid = blockIdx.x;
  const int wg  = (bid & 7) * 128 + (bid >> 3);
  const int bm  = wg & 15;
  const int bn  = wg >> 4;
  const int arow0 = bm * 256;
  const int brow0 = bn * 256;

  const signed char* Ag = A8 + (size_t)arow0 * K_TOT;
  const signed char* Bg = B8 + (size_t)brow0 * K_TOT;

  v4i acc[8][4];
#pragma unroll
  for (int m = 0; m < 8; ++m)
#pragma unroll
    for (int n = 0; n < 4; ++n)
      acc[m][n] = (v4i){0, 0, 0, 0};

  // ---- prologue: stage tile0 + tile1; wait tile0 (4 youngest = tile1 in flight).
  stage_i8(Ag, 0,  &lds[0][0][0], tid);
  stage_i8(Bg, 0,  &lds[0][1][0], tid);
  stage_i8(Ag, 64, &lds[1][0][0], tid);
  stage_i8(Bg, 64, &lds[1][1][0], tid);
  asm volatile("s_waitcnt vmcnt(4)" ::: "memory");
  BAR();

  for (int t = 0; t < NT; ++t) {
    const signed char* At = &lds[t % 3][0][0];
    const signed char* Bt = &lds[t % 3][1][0];
    signed char* L2a = &lds[(t + 2) % 3][0][0];
    signed char* L2b = &lds[(t + 2) % 3][1][0];
    const size_t k2 = (size_t)(t + 2) * 64;

    // Issue next-next tile's staging first (HBM latency starts earliest).
    if (t + 2 < NT) {
      stage_i8(Ag, k2, L2a, tid);
      stage_i8(Bg, k2, L2b, tid);
    }

    // All 12 fragment reads + 32 MFMAs in one unpinned region: the compiler
    // inserts counted lgkmcnt and interleaves MFMA with ds_read drain.
    v4i af[8], bf[4];
#pragma unroll
    for (int m = 0; m < 8; ++m) af[m] = fragi(At, wr * 128 + m * 16 + lr, hi);
#pragma unroll
    for (int n = 0; n < 4; ++n) bf[n] = fragi(Bt, wc * 64 + n * 16 + lr, hi);
#pragma unroll
    for (int m = 0; m < 8; ++m)
#pragma unroll
      for (int n = 0; n < 4; ++n)
        acc[m][n] = __builtin_amdgcn_mfma_i32_16x16x64_i8(af[m], bf[n], acc[m][n], 0, 0, 0);

    // One sync point per K-tile: publish tile t+1 (oldest 4 loads landed),
    // keep tile t+2 (youngest 4) in flight.
    if (t < NT - 2) asm volatile("s_waitcnt vmcnt(4)" ::: "memory");
    else            asm volatile("s_waitcnt vmcnt(0)" ::: "memory");
    BAR();
  }

  // ---- epilogue: y = acc * (sx[row]*scale) + bias.
  // C/D map (dtype-independent): col=lane&15, row=(lane>>4)*4+reg.
  const float s = scale_p[0];
  float bv[4];
#pragma unroll
  for (int n = 0; n < 4; ++n) bv[n] = bias[brow0 + wc * 64 + n * 16 + lr];
#pragma unroll
  for (int mi = 0; mi < 8; ++mi) {
    const int row0 = arow0 + wr * 128 + (mi >> 2) * 64 + (mi & 3) * 16 + hi * 4;
    float sc4[4];
#pragma unroll
    for (int j = 0; j < 4; ++j) sc4[j] = sx[row0 + j] * s;
#pragma unroll
    for (int n = 0; n < 4; ++n) {
      const int col = brow0 + wc * 64 + n * 16 + lr;
      const v4i v = acc[mi][n];
#pragma unroll
      for (int j = 0; j < 4; ++j)
        out[(size_t)(row0 + j) * N_TOT + col] = (float)v[j] * sc4[j] + bv[n];
    }
  }
}

// ---------------- fallback (no workspace): f16 DIRECT 128^2 kernel ----------------

__global__ __launch_bounds__(256) void gemm_direct(
    const float* __restrict__ Xf, const int* __restrict__ Wq,
    const float* __restrict__ scale_p, const float* __restrict__ bias,
    float* __restrict__ out)
{
  __shared__ _Float16 ldsA[128 * 64];
  __shared__ _Float16 ldsB[128 * 64];
  const int tid = threadIdx.x, lane = tid & 63, wave = tid >> 6;
  const int wr = wave >> 1, wc = wave & 1;
  const int bid = blockIdx.x;
  const int wg  = (bid & 7) * 512 + (bid >> 3);
  const int arow0 = (wg & 31) * 128, brow0 = (wg >> 5) * 128;
  f32x4 acc[4][4];
#pragma unroll
  for (int m = 0; m < 4; ++m)
#pragma unroll
    for (int n = 0; n < 4; ++n) acc[m][n] = (f32x4){0.f, 0.f, 0.f, 0.f};
  const int srow = tid >> 3, schunk = tid & 7;
  const int lr = lane & 15, hi = lane >> 4;
  for (int kt = 0; kt < K_TOT / 64; ++kt) {
    const size_t kbase = (size_t)kt * 64;
    __syncthreads();
#pragma unroll
    for (int i = 0; i < 4; ++i) {
      const int row = i * 32 + srow;
      const int p = schunk ^ (row & 7);
      const float* gx = Xf + (size_t)(arow0 + row) * K_TOT + kbase + schunk * 8;
      const int*   gw = Wq + (size_t)(brow0 + row) * K_TOT + kbase + schunk * 8;
      float4 x0 = ((const float4*)gx)[0];
      float4 x1 = ((const float4*)gx)[1];
      int4   w0 = ((const int4*)gw)[0];
      int4   w1 = ((const int4*)gw)[1];
      f16x8 ha = { (_Float16)x0.x, (_Float16)x0.y, (_Float16)x0.z, (_Float16)x0.w,
                   (_Float16)x1.x, (_Float16)x1.y, (_Float16)x1.z, (_Float16)x1.w };
      f16x8 hb = { (_Float16)w0.x, (_Float16)w0.y, (_Float16)w0.z, (_Float16)w0.w,
                   (_Float16)w1.x, (_Float16)w1.y, (_Float16)w1.z, (_Float16)w1.w };
      *(f16x8*)(ldsA + row * 64 + p * 8) = ha;
      *(f16x8*)(ldsB + row * 64 + p * 8) = hb;
    }
    __syncthreads();
#pragma unroll
    for (int s2 = 0; s2 < 2; ++s2) {
      f16x8 af2[4], bf2[4];
#pragma unroll
      for (int m = 0; m < 4; ++m) {
        const int r = wr * 64 + m * 16 + lr;
        af2[m] = *(const f16x8*)(ldsA + r * 64 + (((s2 * 4 + hi) ^ (r & 7)) * 8));
      }
#pragma unroll
      for (int n = 0; n < 4; ++n) {
        const int r = wc * 64 + n * 16 + lr;
        bf2[n] = *(const f16x8*)(ldsB + r * 64 + (((s2 * 4 + hi) ^ (r & 7)) * 8));
      }
#pragma unroll
      for (int m = 0; m < 4; ++m)
#pragma unroll
        for (int n = 0; n < 4; ++n)
          acc[m][n] = __builtin_amdgcn_mfma_f32_16x16x32_f16(af2[m], bf2[n], acc[m][n], 0, 0, 0);
    }
  }
  const float s = scale_p[0];
#pragma unroll
  for (int n = 0; n < 4; ++n) {
    const int col = brow0 + wc * 64 + n * 16 + lr;
    const float bvv = bias[col];
#pragma unroll
    for (int m = 0; m < 4; ++m) {
      const int row0 = arow0 + wr * 64 + m * 16 + hi * 4;
      const f32x4 v = acc[m][n];
#pragma unroll
      for (int j = 0; j < 4; ++j)
        out[(size_t)(row0 + j) * N_TOT + col] = v[j] * s + bvv;
    }
  }
}

// ---------------- launch ----------------

extern "C" void kernel_launch(void* const* d_in, const int* in_sizes, int n_in,
                              void* d_out, int out_size, void* d_ws, size_t ws_size,
                              hipStream_t stream) {
  const float* x     = (const float*)d_in[0];
  const int*   wq    = (const int*)d_in[1];
  const float* scale = (const float*)d_in[2];
  const float* bias  = (const float*)d_in[3];
  float*       out   = (float*)d_out;

  const size_t nA = (size_t)M_TOT * K_TOT;   // 16.7M
  const size_t nB = (size_t)N_TOT * K_TOT;   // 67.1M
  const size_t need = nA + nB + M_TOT * sizeof(float);  // ~84 MiB

  if (ws_size >= need) {
    signed char* A8 = (signed char*)d_ws;
    signed char* B8 = A8 + nA;
    float*       sx = (float*)(B8 + nB);
    cvt_x_i8<<<M_TOT, 256, 0, stream>>>(x, A8, sx);
    cvt_w_i8<<<2048, 256, 0, stream>>>(wq, B8, (int)(nB / 16));
    gemm_i8<<<(M_TOT / 256) * (N_TOT / 256), 512, 0, stream>>>(A8, B8, sx, scale, bias, out);
  } else {
    gemm_direct<<<(M_TOT / 128) * (N_TOT / 128), 256, 0, stream>>>(x, wq, scale, bias, out);
  }
}

// Round 7
// 417.352 us; speedup vs baseline: 6.4273x; 1.0359x over previous
//
#include <hip/hip_runtime.h>
#include <stdint.h>
#include <stddef.h>

// QuantizedColumnParallel: y[4096,16384] = x[4096,4096] @ (wq[16384,4096]*scale)^T + bias
// R7: register-pipelined fragments. R4/R6 showed LDS-read segment (1152 cyc/CU/tile)
// and MFMA segment (1306 cyc) SUM because read(t)->mfma(t) is a true dependency and
// MFMA issue is backpressured. Fix: read frags(t+1) while mfma(t) drains (independent
// ops in one region). 4 LDS buffers (128 KB), stage t+3 during t, vmcnt(4) ledger.

#define M_TOT 4096
#define N_TOT 16384
#define K_TOT 4096
#define NT    64          // K-tiles

typedef __attribute__((ext_vector_type(4))) int      v4i;
typedef __attribute__((ext_vector_type(8))) _Float16 f16x8;
typedef __attribute__((ext_vector_type(4))) float    f32x4;

#define GLOAD_LDS16(g, l) __builtin_amdgcn_global_load_lds(                  \
    (const __attribute__((address_space(1))) void*)(g),                      \
    (__attribute__((address_space(3))) void*)(l), 16, 0, 0)

// ---------------- conversion pre-passes ----------------

// x: one block per row (4096 f32). Row max -> sx, quantize to int8.
__global__ __launch_bounds__(256) void cvt_x_i8(const float* __restrict__ x,
                                                signed char* __restrict__ o,
                                                float* __restrict__ sx) {
  const int row = blockIdx.x;
  const int tid = threadIdx.x;
  const float* xr = x + (size_t)row * K_TOT;
  float4 v[4];
  float mx = 0.f;
#pragma unroll
  for (int j = 0; j < 4; ++j) {
    v[j] = ((const float4*)xr)[tid * 4 + j];
    mx = fmaxf(mx, fmaxf(fmaxf(fabsf(v[j].x), fabsf(v[j].y)),
                         fmaxf(fabsf(v[j].z), fabsf(v[j].w))));
  }
#pragma unroll
  for (int off = 32; off; off >>= 1) mx = fmaxf(mx, __shfl_xor(mx, off));
  __shared__ float wm[4];
  if ((tid & 63) == 0) wm[tid >> 6] = mx;
  __syncthreads();
  const float m4 = fmaxf(fmaxf(wm[0], wm[1]), fmaxf(wm[2], wm[3]));
  const float smax = fmaxf(m4, 1e-6f);
  const float inv  = 127.0f / smax;
  if (tid == 0) sx[row] = smax / 127.0f;
  int p[4];
#pragma unroll
  for (int j = 0; j < 4; ++j) {
    int q0 = (int)rintf(v[j].x * inv), q1 = (int)rintf(v[j].y * inv);
    int q2 = (int)rintf(v[j].z * inv), q3 = (int)rintf(v[j].w * inv);
    q0 = max(-127, min(127, q0)); q1 = max(-127, min(127, q1));
    q2 = max(-127, min(127, q2)); q3 = max(-127, min(127, q3));
    p[j] = (q0 & 255) | ((q1 & 255) << 8) | ((q2 & 255) << 16) | (q3 << 24);
  }
  ((int4*)(o + (size_t)row * K_TOT))[tid] = make_int4(p[0], p[1], p[2], p[3]);
}

// w: int32 (-127..127) -> int8, 16 elems/thread.
__global__ __launch_bounds__(256) void cvt_w_i8(const int* __restrict__ w,
                                                signed char* __restrict__ o, int n16) {
  const int stride = gridDim.x * blockDim.x;
  for (int i = blockIdx.x * blockDim.x + threadIdx.x; i < n16; i += stride) {
    int p[4];
#pragma unroll
    for (int j = 0; j < 4; ++j) {
      int4 a = ((const int4*)w)[i * 4 + j];
      p[j] = (a.x & 255) | ((a.y & 255) << 8) | ((a.z & 255) << 16) | (a.w << 24);
    }
    ((int4*)o)[i] = make_int4(p[0], p[1], p[2], p[3]);
  }
}

// ---------------- i8 GEMM: 256^2 tile, reg-pipelined frags, 4 LDS buffers ----------------

// Stage one 256x64-byte region (16 KiB): 2 x global_load_lds(16B)/thread.
// LDS dest linear; XOR swizzle on GLOBAL source chunk (rule #21). Conflict-free
// verified R3/R4/R6 (SQ_LDS_BANK_CONFLICT = 0).
__device__ __forceinline__ void stage_i8(const signed char* __restrict__ g,
                                         size_t kbyte, signed char* l, int tid) {
#pragma unroll
  for (int j = 0; j < 2; ++j) {
    const int ci  = j * 512 + tid;       // 0..1023 16B-chunks
    const int row = ci >> 2;             // 0..255
    const int sc  = (ci & 3) ^ ((row >> 1) & 3);
    GLOAD_LDS16(g + (size_t)row * K_TOT + kbyte + sc * 16, l + ci * 16);
  }
}

// Swizzled fragment read: row r, 16B chunk hi (0..3). 2-way aliasing = free.
__device__ __forceinline__ v4i fragi(const signed char* region, int r, int hi) {
  return *(const v4i*)(region + r * 64 + ((hi ^ ((r >> 1) & 3)) << 4));
}

#define BAR()  do { __builtin_amdgcn_s_barrier(); \
                    __builtin_amdgcn_sched_barrier(0); } while (0)

#define READ_FRAGS(A, B, At, Bt)                                              \
  do {                                                                        \
    _Pragma("unroll")                                                         \
    for (int m = 0; m < 8; ++m) A[m] = fragi(At, wr * 128 + m * 16 + lr, hi); \
    _Pragma("unroll")                                                         \
    for (int n = 0; n < 4; ++n) B[n] = fragi(Bt, wc * 64 + n * 16 + lr, hi);  \
  } while (0)

#define MFMA_TILE(A, B)                                                       \
  do {                                                                        \
    _Pragma("unroll")                                                         \
    for (int m = 0; m < 8; ++m)                                               \
      _Pragma("unroll")                                                       \
      for (int n = 0; n < 4; ++n)                                             \
        acc[m][n] = __builtin_amdgcn_mfma_i32_16x16x64_i8(A[m], B[n],         \
                                                          acc[m][n], 0, 0, 0);\
  } while (0)

__global__ __launch_bounds__(512, 2) void gemm_i8(
    const signed char* __restrict__ A8, const signed char* __restrict__ B8,
    const float* __restrict__ sx, const float* __restrict__ scale_p,
    const float* __restrict__ bias, float* __restrict__ out)
{
  // lds[buf(4)][A=0|B=1][256*64 bytes] = 128 KiB -> 1 block/CU
  __shared__ __align__(16) signed char lds[4][2][16384];

  const int tid  = threadIdx.x;
  const int lane = tid & 63;
  const int wave = tid >> 6;
  const int wr = wave >> 2;            // 0..1 (M)
  const int wc = wave & 3;             // 0..3 (N)
  const int lr = lane & 15;
  const int hi = lane >> 4;

  // XCD-aware swizzle: 1024 wg, 8 XCDs, 128 contiguous per XCD; bm fast.
  const int bid = blockIdx.x;
  const int wg  = (bid & 7) * 128 + (bid >> 3);
  const int bm  = wg & 15;
  const int bn  = wg >> 4;
  const int arow0 = bm * 256;
  const int brow0 = bn * 256;

  const signed char* Ag = A8 + (size_t)arow0 * K_TOT;
  const signed char* Bg = B8 + (size_t)brow0 * K_TOT;

  v4i acc[8][4];
#pragma unroll
  for (int m = 0; m < 8; ++m)
#pragma unroll
    for (int n = 0; n < 4; ++n)
      acc[m][n] = (v4i){0, 0, 0, 0};

  // ---- prologue: stage tiles 0,1,2; vmcnt(4) => 0,1 landed, 2 in flight.
  stage_i8(Ag, 0,   &lds[0][0][0], tid);
  stage_i8(Bg, 0,   &lds[0][1][0], tid);
  stage_i8(Ag, 64,  &lds[1][0][0], tid);
  stage_i8(Bg, 64,  &lds[1][1][0], tid);
  stage_i8(Ag, 128, &lds[2][0][0], tid);
  stage_i8(Bg, 128, &lds[2][1][0], tid);
  asm volatile("s_waitcnt vmcnt(4)" ::: "memory");
  BAR();

  v4i a0[8], b0[4], a1[8], b1[4];
  READ_FRAGS(a0, b0, &lds[0][0][0], &lds[0][1][0]);   // tile 0

  for (int t = 0; t < NT; t += 2) {
    // ---- half A: compute tile t with F0; read F1 <- tile t+1; stage t+3.
    {
      if (t + 3 < NT) {
        const size_t k3 = (size_t)(t + 3) * 64;
        stage_i8(Ag, k3, &lds[(t + 3) & 3][0][0], tid);
        stage_i8(Bg, k3, &lds[(t + 3) & 3][1][0], tid);
      }
      const signed char* At1 = &lds[(t + 1) & 3][0][0];
      const signed char* Bt1 = &lds[(t + 1) & 3][1][0];
      READ_FRAGS(a1, b1, At1, Bt1);          // independent of mfma below
      MFMA_TILE(a0, b0);
      // need stage(t+2) landed for next half's reads; keep stage(t+3) in flight.
      if (t + 3 < NT) asm volatile("s_waitcnt vmcnt(4)" ::: "memory");
      else            asm volatile("s_waitcnt vmcnt(0)" ::: "memory");
      BAR();
    }
    // ---- half B: compute tile t+1 with F1; read F0 <- tile t+2; stage t+4.
    {
      if (t + 4 < NT) {
        const size_t k4 = (size_t)(t + 4) * 64;
        stage_i8(Ag, k4, &lds[(t + 4) & 3][0][0], tid);
        stage_i8(Bg, k4, &lds[(t + 4) & 3][1][0], tid);
      }
      if (t + 2 < NT) {
        const signed char* At2 = &lds[(t + 2) & 3][0][0];
        const signed char* Bt2 = &lds[(t + 2) & 3][1][0];
        READ_FRAGS(a0, b0, At2, Bt2);
      }
      MFMA_TILE(a1, b1);
      // need stage(t+3) landed for next half A's reads.
      if (t + 4 < NT) asm volatile("s_waitcnt vmcnt(4)" ::: "memory");
      else            asm volatile("s_waitcnt vmcnt(0)" ::: "memory");
      BAR();
    }
  }

  // ---- epilogue: y = acc * (sx[row]*scale) + bias.
  // C/D map (dtype-independent): col=lane&15, row=(lane>>4)*4+reg.
  const float s = scale_p[0];
  float bv[4];
#pragma unroll
  for (int n = 0; n < 4; ++n) bv[n] = bias[brow0 + wc * 64 + n * 16 + lr];
#pragma unroll
  for (int mi = 0; mi < 8; ++mi) {
    const int row0 = arow0 + wr * 128 + (mi >> 2) * 64 + (mi & 3) * 16 + hi * 4;
    float sc4[4];
#pragma unroll
    for (int j = 0; j < 4; ++j) sc4[j] = sx[row0 + j] * s;
#pragma unroll
    for (int n = 0; n < 4; ++n) {
      const int col = brow0 + wc * 64 + n * 16 + lr;
      const v4i v = acc[mi][n];
#pragma unroll
      for (int j = 0; j < 4; ++j)
        out[(size_t)(row0 + j) * N_TOT + col] = (float)v[j] * sc4[j] + bv[n];
    }
  }
}

// ---------------- fallback (no workspace): f16 DIRECT 128^2 kernel ----------------

__global__ __launch_bounds__(256) void gemm_direct(
    const float* __restrict__ Xf, const int* __restrict__ Wq,
    const float* __restrict__ scale_p, const float* __restrict__ bias,
    float* __restrict__ out)
{
  __shared__ _Float16 ldsA[128 * 64];
  __shared__ _Float16 ldsB[128 * 64];
  const int tid = threadIdx.x, lane = tid & 63, wave = tid >> 6;
  const int wr = wave >> 1, wc = wave & 1;
  const int bid = blockIdx.x;
  const int wg  = (bid & 7) * 512 + (bid >> 3);
  const int arow0 = (wg & 31) * 128, brow0 = (wg >> 5) * 128;
  f32x4 acc[4][4];
#pragma unroll
  for (int m = 0; m < 4; ++m)
#pragma unroll
    for (int n = 0; n < 4; ++n) acc[m][n] = (f32x4){0.f, 0.f, 0.f, 0.f};
  const int srow = tid >> 3, schunk = tid & 7;
  const int lr = lane & 15, hi = lane >> 4;
  for (int kt = 0; kt < K_TOT / 64; ++kt) {
    const size_t kbase = (size_t)kt * 64;
    __syncthreads();
#pragma unroll
    for (int i = 0; i < 4; ++i) {
      const int row = i * 32 + srow;
      const int p = schunk ^ (row & 7);
      const float* gx = Xf + (size_t)(arow0 + row) * K_TOT + kbase + schunk * 8;
      const int*   gw = Wq + (size_t)(brow0 + row) * K_TOT + kbase + schunk * 8;
      float4 x0 = ((const float4*)gx)[0];
      float4 x1 = ((const float4*)gx)[1];
      int4   w0 = ((const int4*)gw)[0];
      int4   w1 = ((const int4*)gw)[1];
      f16x8 ha = { (_Float16)x0.x, (_Float16)x0.y, (_Float16)x0.z, (_Float16)x0.w,
                   (_Float16)x1.x, (_Float16)x1.y, (_Float16)x1.z, (_Float16)x1.w };
      f16x8 hb = { (_Float16)w0.x, (_Float16)w0.y, (_Float16)w0.z, (_Float16)w0.w,
                   (_Float16)w1.x, (_Float16)w1.y, (_Float16)w1.z, (_Float16)w1.w };
      *(f16x8*)(ldsA + row * 64 + p * 8) = ha;
      *(f16x8*)(ldsB + row * 64 + p * 8) = hb;
    }
    __syncthreads();
#pragma unroll
    for (int s2 = 0; s2 < 2; ++s2) {
      f16x8 af2[4], bf2[4];
#pragma unroll
      for (int m = 0; m < 4; ++m) {
        const int r = wr * 64 + m * 16 + lr;
        af2[m] = *(const f16x8*)(ldsA + r * 64 + (((s2 * 4 + hi) ^ (r & 7)) * 8));
      }
#pragma unroll
      for (int n = 0; n < 4; ++n) {
        const int r = wc * 64 + n * 16 + lr;
        bf2[n] = *(const f16x8*)(ldsB + r * 64 + (((s2 * 4 + hi) ^ (r & 7)) * 8));
      }
#pragma unroll
      for (int m = 0; m < 4; ++m)
#pragma unroll
        for (int n = 0; n < 4; ++n)
          acc[m][n] = __builtin_amdgcn_mfma_f32_16x16x32_f16(af2[m], bf2[n], acc[m][n], 0, 0, 0);
    }
  }
  const float s = scale_p[0];
#pragma unroll
  for (int n = 0; n < 4; ++n) {
    const int col = brow0 + wc * 64 + n * 16 + lr;
    const float bvv = bias[col];
#pragma unroll
    for (int m = 0; m < 4; ++m) {
      const int row0 = arow0 + wr * 64 + m * 16 + hi * 4;
      const f32x4 v = acc[m][n];
#pragma unroll
      for (int j = 0; j < 4; ++j)
        out[(size_t)(row0 + j) * N_TOT + col] = v[j] * s + bvv;
    }
  }
}

// ---------------- launch ----------------

extern "C" void kernel_launch(void* const* d_in, const int* in_sizes, int n_in,
                              void* d_out, int out_size, void* d_ws, size_t ws_size,
                              hipStream_t stream) {
  const float* x     = (const float*)d_in[0];
  const int*   wq    = (const int*)d_in[1];
  const float* scale = (const float*)d_in[2];
  const float* bias  = (const float*)d_in[3];
  float*       out   = (float*)d_out;

  const size_t nA = (size_t)M_TOT * K_TOT;   // 16.7M
  const size_t nB = (size_t)N_TOT * K_TOT;   // 67.1M
  const size_t need = nA + nB + M_TOT * sizeof(float);  // ~84 MiB

  if (ws_size >= need) {
    signed char* A8 = (signed char*)d_ws;
    signed char* B8 = A8 + nA;
    float*       sx = (float*)(B8 + nB);
    cvt_x_i8<<<M_TOT, 256, 0, stream>>>(x, A8, sx);
    cvt_w_i8<<<2048, 256, 0, stream>>>(wq, B8, (int)(nB / 16));
    gemm_i8<<<(M_TOT / 256) * (N_TOT / 256), 512, 0, stream>>>(A8, B8, sx, scale, bias, out);
  } else {
    gemm_direct<<<(M_TOT / 128) * (N_TOT / 128), 256, 0, stream>>>(x, wq, scale, bias, out);
  }
}